// Round 7
// baseline (915.849 us; speedup 1.0000x reference)
//
#include <hip/hip_runtime.h>
#include <hip/hip_bf16.h>
#include <math.h>

typedef __bf16 bf16_t;
typedef __bf16 bf16x4 __attribute__((ext_vector_type(4)));
typedef __bf16 bf16x8 __attribute__((ext_vector_type(8)));
typedef float  f32x4  __attribute__((ext_vector_type(4)));

#define DIN   3072
#define NOUT  24576
#define HALF  12288
#define MTOK  4096
#define BK    64
#define NT    48          // DIN / BK

#define GLD16(gp, lp) \
    __builtin_amdgcn_global_load_lds((const __attribute__((address_space(1))) void*)(gp), \
                                     (__attribute__((address_space(3))) void*)(lp), 16, 0, 0)

#define BAR()    __builtin_amdgcn_s_barrier()
#define WAITV(N) asm volatile("s_waitcnt vmcnt(" #N ")" ::: "memory")
#define SCHED0() __builtin_amdgcn_sched_barrier(0)

// ---------------- K1: per-token activation int4 fake-quant -> bf16 ----------------
__global__ __launch_bounds__(256) void k_quant_x(const float* __restrict__ x,
                                                 bf16_t* __restrict__ xq) {
    int m = blockIdx.x;
    int t = threadIdx.x;
    const float4* row = reinterpret_cast<const float4*>(x + (size_t)m * DIN);
    float4 v[3];
    float vm = 0.f;
#pragma unroll
    for (int i = 0; i < 3; ++i) {
        v[i] = row[t + i * 256];
        vm = fmaxf(vm, fmaxf(fmaxf(fabsf(v[i].x), fabsf(v[i].y)),
                             fmaxf(fabsf(v[i].z), fabsf(v[i].w))));
    }
#pragma unroll
    for (int d = 1; d < 64; d <<= 1) vm = fmaxf(vm, __shfl_xor(vm, d));
    __shared__ float sm[4];
    if ((t & 63) == 0) sm[t >> 6] = vm;
    __syncthreads();
    vm = fmaxf(fmaxf(sm[0], sm[1]), fmaxf(sm[2], sm[3]));
    float s = fmaxf(vm * (1.f / 7.f), 1e-8f);
    float inv = 1.f / s;
    bf16x4* orow = reinterpret_cast<bf16x4*>(xq + (size_t)m * DIN);
#pragma unroll
    for (int i = 0; i < 3; ++i) {
        bf16x4 o;
        o[0] = (bf16_t)(fminf(fmaxf(rintf(v[i].x * inv), -8.f), 7.f) * s);
        o[1] = (bf16_t)(fminf(fmaxf(rintf(v[i].y * inv), -8.f), 7.f) * s);
        o[2] = (bf16_t)(fminf(fmaxf(rintf(v[i].z * inv), -8.f), 7.f) * s);
        o[3] = (bf16_t)(fminf(fmaxf(rintf(v[i].w * inv), -8.f), 7.f) * s);
        orow[t + i * 256] = o;
    }
}

// ---------------- K2: per-(row, group-of-64) weight int4 fake-quant -> bf16 -------
__global__ __launch_bounds__(256) void k_quant_w(const float* __restrict__ w,
                                                 bf16_t* __restrict__ wq) {
    size_t idx = (size_t)blockIdx.x * 256 + threadIdx.x;  // float4 index
    float4 v = reinterpret_cast<const float4*>(w)[idx];
    float vm = fmaxf(fmaxf(fabsf(v.x), fabsf(v.y)), fmaxf(fabsf(v.z), fabsf(v.w)));
    vm = fmaxf(vm, __shfl_xor(vm, 1));
    vm = fmaxf(vm, __shfl_xor(vm, 2));
    vm = fmaxf(vm, __shfl_xor(vm, 4));
    vm = fmaxf(vm, __shfl_xor(vm, 8));
    float s = fmaxf(vm * (1.f / 7.f), 1e-8f);
    float inv = 1.f / s;
    bf16x4 o;
    o[0] = (bf16_t)(fminf(fmaxf(rintf(v.x * inv), -8.f), 7.f) * s);
    o[1] = (bf16_t)(fminf(fmaxf(rintf(v.y * inv), -8.f), 7.f) * s);
    o[2] = (bf16_t)(fminf(fmaxf(rintf(v.z * inv), -8.f), 7.f) * s);
    o[3] = (bf16_t)(fminf(fmaxf(rintf(v.w * inv), -8.f), 7.f) * s);
    reinterpret_cast<bf16x4*>(wq)[idx] = o;
}

// ---------------- K3: T = x @ lora_down^T  (full-precision x), bf16 out -----------
__global__ __launch_bounds__(256) void k_lora_t(const float* __restrict__ x,
                                                const float* __restrict__ ld,
                                                bf16_t* __restrict__ T) {
    int r = threadIdx.x & 31;
    int m = blockIdx.x * 8 + (threadIdx.x >> 5);
    const float4* xr = reinterpret_cast<const float4*>(x + (size_t)m * DIN);
    const float4* lr = reinterpret_cast<const float4*>(ld + (size_t)r * DIN);
    float acc = 0.f;
#pragma unroll 4
    for (int i = 0; i < DIN / 4; ++i) {
        float4 a = xr[i], b = lr[i];
        acc += a.x * b.x + a.y * b.y + a.z * b.z + a.w * b.w;
    }
    T[(size_t)m * 32 + r] = (bf16_t)acc;
}

// ---------------- K3b: cast lora_up f32 -> bf16 -----------------------------------
__global__ __launch_bounds__(256) void k_cvt_lu(const float* __restrict__ lu,
                                                bf16_t* __restrict__ lub) {
    size_t idx = (size_t)blockIdx.x * 256 + threadIdx.x;  // float4 index
    float4 v = reinterpret_cast<const float4*>(lu)[idx];
    bf16x4 o;
    o[0] = (bf16_t)v.x; o[1] = (bf16_t)v.y; o[2] = (bf16_t)v.z; o[3] = (bf16_t)v.w;
    reinterpret_cast<bf16x4*>(lub)[idx] = o;
}

// ---------------- K4: minimum-2-phase dbuf fused GEMM (T2+T3-minimal) -------------
// Tile 256 rows x (128 H + 128 G cols). 8 waves: 0-3 H, 4-7 G, 2x2 each.
// LDS dbuf 2 x {A0 16K | A1 16K | BH 16K | BG 16K} = 128 KB.
// Per K-tile: STG(next tile, 8 GLD16) issued FIRST (slack = full MFMA burst),
// then 24 ds_read + 64 MFMA with compiler-managed lgkmcnt (no mid-tile barriers),
// then ONE WAITV(0)+BAR. WAR safe: buf^1's reads all retired before prior barrier.

#define LOADA(dst, mh, base)                                                  \
    _Pragma("unroll")                                                         \
    for (int _i = 0; _i < 4; ++_i) {                                          \
        _Pragma("unroll")                                                     \
        for (int _ks = 0; _ks < 2; ++_ks) {                                   \
            int _ra = (mh) * 128 + wr * 64 + _i * 16 + l15;                   \
            dst[_i][_ks] = *(const bf16x8*)((base) + _ra * 128 +              \
                                            (((_ks * 4 + lhi) ^ lk) << 4));   \
        }                                                                     \
    }

#define LOADB(dst, nh, base)                                                  \
    _Pragma("unroll")                                                         \
    for (int _j = 0; _j < 2; ++_j) {                                          \
        _Pragma("unroll")                                                     \
        for (int _ks = 0; _ks < 2; ++_ks) {                                   \
            int _rb = wc * 64 + ((nh) * 2 + _j) * 16 + l15;                   \
            dst[_j][_ks] = *(const bf16x8*)((base) + _rb * 128 +              \
                                            (((_ks * 4 + lhi) ^ lk) << 4));   \
        }                                                                     \
    }

#define MFMAQ(mh, nh, A, B)                                                   \
    _Pragma("unroll")                                                         \
    for (int _i = 0; _i < 4; ++_i) {                                          \
        _Pragma("unroll")                                                     \
        for (int _j = 0; _j < 2; ++_j) {                                      \
            _Pragma("unroll")                                                 \
            for (int _ks = 0; _ks < 2; ++_ks) {                               \
                acc[(mh) * 4 + _i][(nh) * 2 + _j] =                           \
                    __builtin_amdgcn_mfma_f32_16x16x32_bf16(                  \
                        A[_i][_ks], B[_j][_ks],                               \
                        acc[(mh) * 4 + _i][(nh) * 2 + _j], 0, 0, 0);          \
            }                                                                 \
        }                                                                     \
    }

#define STG(pl, ph, off)                                                      \
    do {                                                                      \
        GLD16((pl), swc + (off) + wq4);                                       \
        GLD16((ph), swc + (off) + wq4 + 8192);                                \
    } while (0)

__global__ __launch_bounds__(512, 2) void k_gemm(const bf16_t* __restrict__ xq,
                                                 const bf16_t* __restrict__ wq,
                                                 const bf16_t* __restrict__ T,
                                                 const bf16_t* __restrict__ lub,
                                                 float* __restrict__ out) {
    __shared__ __align__(16) char smem[131072];

    const int tid = threadIdx.x, lane = tid & 63, w = tid >> 6;
    const int half = w >> 2;                 // 0 = H group, 1 = G group
    const int wr = (w >> 1) & 1, wc = w & 1; // 2x2 within group
    const int l15 = lane & 15, lhi = lane >> 4, lk = lane & 7;
    const int wq4 = w * 1024;                // wave-uniform LDS sub-base

    // XCD-bijective swizzle: nwg = 1536, 1536 % 8 == 0
    const int nwg = gridDim.x;
    const int cpx = nwg >> 3;
    const int swz = ((int)blockIdx.x & 7) * cpx + ((int)blockIdx.x >> 3);
    const int mt = swz & 15, nt = swz >> 4;  // mt fast: neighbors share B panels
    const int m0 = mt * 256, c0 = nt * 128;

    f32x4 acc[8][4];
#pragma unroll
    for (int i = 0; i < 8; ++i)
#pragma unroll
        for (int j = 0; j < 4; ++j) acc[i][j] = (f32x4){0.f, 0.f, 0.f, 0.f};

    // hoisted per-thread global source pointers (both-sides swizzle folded in;
    // row+64k == row mod 8 -> same XOR column for lo/hi chunk)
    const int srow = tid >> 3;
    const int sgc = ((tid & 7) ^ (srow & 7)) * 8;
    const bf16_t* pA0l = xq + (size_t)(m0 + srow) * DIN + sgc;
    const bf16_t* pA0h = pA0l + (size_t)64 * DIN;
    const bf16_t* pA1l = pA0l + (size_t)128 * DIN;
    const bf16_t* pA1h = pA0l + (size_t)192 * DIN;
    const bf16_t* pHl  = wq + (size_t)(c0 + srow) * DIN + sgc;
    const bf16_t* pHh  = pHl + (size_t)64 * DIN;
    const bf16_t* pGl  = pHl + (size_t)HALF * DIN;
    const bf16_t* pGh  = pGl + (size_t)64 * DIN;

    // ---- prologue: stage tile 0 into buf0 ----
    {
        char* swc = (char*)smem;             // buf0
        STG(pA0l, pA0h, 0);
        STG(pHl, pHh, 32768);
        STG(pGl, pGh, 49152);
        STG(pA1l, pA1h, 16384);
    }
    pA0l += BK; pA0h += BK; pA1l += BK; pA1h += BK;
    pHl += BK; pHh += BK; pGl += BK; pGh += BK;
    WAITV(0);
    BAR();
    SCHED0();

    int cur = 0;
    for (int t = 0; t < NT; ++t) {
        const char* sAc = (const char*)smem + (cur << 16);
        const char* sBc = sAc + 32768 + (half << 14);
        char* swc = (char*)smem + ((cur ^ 1) << 16);

        // stage next K-tile early (last iter re-stages NT-1 into dead buffer)
        STG(pA0l, pA0h, 0);
        STG(pHl, pHh, 32768);
        STG(pGl, pGh, 49152);
        STG(pA1l, pA1h, 16384);

        // reads + MFMA, compiler-managed fine-grained lgkmcnt; no mid-tile barrier
        bf16x8 a0[4][2], a1[4][2], b0[2][2], b1[2][2];
        LOADB(b0, 0, sBc);
        LOADB(b1, 1, sBc);
        LOADA(a0, 0, sAc);
        MFMAQ(0, 0, a0, b0);
        MFMAQ(0, 1, a0, b1);
        LOADA(a1, 1, sAc);
        MFMAQ(1, 0, a1, b0);
        MFMAQ(1, 1, a1, b1);

        // close tile: DMA landed (full-burst slack) + cross-wave visibility
        WAITV(0);
        BAR();
        SCHED0();

        const int adv = (t + 2 < NT) ? BK : 0;
        pA0l += adv; pA0h += adv; pA1l += adv; pA1h += adv;
        pHl += adv; pHh += adv; pGl += adv; pGh += adv;
        cur ^= 1;
    }

    // ---- LoRA correction: one K=32 MFMA per fragment (RANK == 32) ----
    {
        bf16x8 tf[8];
#pragma unroll
        for (int m = 0; m < 8; ++m) {
            int row = m0 + (m >> 2) * 128 + wr * 64 + (m & 3) * 16 + l15;
            tf[m] = *reinterpret_cast<const bf16x8*>(T + (size_t)row * 32 + lhi * 8);
        }
#pragma unroll
        for (int n = 0; n < 4; ++n) {
            int ocol = c0 + half * HALF + wc * 64 + n * 16 + l15;
            bf16x8 lu = *reinterpret_cast<const bf16x8*>(lub + (size_t)ocol * 32 + lhi * 8);
#pragma unroll
            for (int m = 0; m < 8; ++m)
                acc[m][n] = __builtin_amdgcn_mfma_f32_16x16x32_bf16(tf[m], lu, acc[m][n], 0, 0, 0);
        }
    }

    // ---- GEGLU epilogue via LDS exchange (reuse all 128 KB as [256][128] f32) ----
    __syncthreads();          // all staging drained by final in-loop WAITV(0)+BAR
    float* exch = (float*)smem;
    if (half) {
#pragma unroll
        for (int m = 0; m < 8; ++m)
#pragma unroll
            for (int n = 0; n < 4; ++n) {
                int col = wc * 64 + n * 16 + l15;
#pragma unroll
                for (int r = 0; r < 4; ++r) {
                    int row = (m >> 2) * 128 + wr * 64 + (m & 3) * 16 + lhi * 4 + r;
                    float g = acc[m][n][r];
                    float gl = 0.5f * g * (1.0f + erff(g * 0.70710678118654752f));
                    exch[row * 128 + (col ^ (((row >> 2) & 3) << 4))] = gl;
                }
            }
    }
    __syncthreads();
    if (!half) {
#pragma unroll
        for (int m = 0; m < 8; ++m)
#pragma unroll
            for (int n = 0; n < 4; ++n) {
                int col = wc * 64 + n * 16 + l15;
#pragma unroll
                for (int r = 0; r < 4; ++r) {
                    int row = (m >> 2) * 128 + wr * 64 + (m & 3) * 16 + lhi * 4 + r;
                    float gl = exch[row * 128 + (col ^ (((row >> 2) & 3) << 4))];
                    out[(size_t)(m0 + row) * HALF + c0 + col] = acc[m][n][r] * gl;
                }
            }
    }
}

extern "C" void kernel_launch(void* const* d_in, const int* in_sizes, int n_in,
                              void* d_out, int out_size, void* d_ws, size_t ws_size,
                              hipStream_t stream) {
    const float* x  = (const float*)d_in[0];   // [1,4096,3072]
    const float* wr = (const float*)d_in[1];   // [24576,3072]
    const float* ld = (const float*)d_in[2];   // [32,3072]
    const float* lu = (const float*)d_in[3];   // [24576,32]
    float* out = (float*)d_out;                // [4096,12288] f32

    bf16_t* xq  = (bf16_t*)d_ws;
    bf16_t* wq  = xq + (size_t)MTOK * DIN;
    bf16_t* T   = wq + (size_t)NOUT * DIN;
    bf16_t* lub = T  + (size_t)MTOK * 32;

    k_quant_x<<<MTOK, 256, 0, stream>>>(x, xq);
    k_quant_w<<<(NOUT * (DIN / 4)) / 256, 256, 0, stream>>>(wr, wq);
    k_lora_t<<<MTOK / 8, 256, 0, stream>>>(x, ld, T);
    k_cvt_lu<<<(NOUT * 32 / 4) / 256, 256, 0, stream>>>(lu, lub);
    k_gemm<<<(MTOK / 256) * (HALF / 128), 512, 0, stream>>>(xq, wq, T, lub, out);
}